// Round 12
// baseline (457.307 us; speedup 1.0000x reference)
//
#include <hip/hip_runtime.h>
#include <math.h>

// MoE gate: bf16x3 split GEMM on 32x32x16 MFMA (2x FLOP per LDS byte vs
// 16x16x32), 8 waves = 4 expert-groups x 2 K-parities, 4-slot LDS ring
// (160 KB), + fp32 gating with margin flags + exact fp64 repair.
// T=16384, H=7168, E=256, 8 groups, top4 groups, top8 experts.
// Output (float*): [0..T*8) = topk_idx as float, [T*8..2*T*8) = topk_weight.

typedef __bf16 bf16_t;
typedef __bf16 bf16x8 __attribute__((ext_vector_type(8)));
typedef float  f32x16 __attribute__((ext_vector_type(16)));

constexpr int T_TOT = 16384;
constexpr int HID   = 7168;
constexpr int NEXP  = 256;

constexpr int BM1  = 64;
constexpr int BK1  = 32;
constexpr int NCH1 = HID / BK1;   // 224
constexpr int NPH  = NCH1 / 2;    // 112 phases (2 chunks each)

// LDS: 4 B-slots x 32 KB (16 frags x 1KB hi | 16 x 1KB lo) at s*32768,
//      4 A-slots x 8 KB  (4 frags x 1KB hi | lo) at 131072 + s*8192.
// slot = chunk % 4. Epilogue alias: logits f32 [64][264] = 67584 B.
constexpr int A_BASE  = 131072;
constexpr int SMEM_SZ = 163840;
constexpr int LSTR    = 264;

constexpr float ETHR = 1.2e-5f;
constexpr float GTHR = 2.4e-5f;

constexpr int LISTCAP = 16384;
constexpr int KSEG = 16;
constexpr int SEGK = HID / KSEG;  // 448
constexpr int TB2  = 32;
constexpr int TBG  = 8;

// ---------------------------------------------------------------------------
__device__ __forceinline__ void async16(const void* g, void* l)
{
    auto* lds = reinterpret_cast<__attribute__((address_space(3))) unsigned int*>(
        reinterpret_cast<uintptr_t>(l));
    const auto* gl = reinterpret_cast<const __attribute__((address_space(1))) unsigned int*>(
        reinterpret_cast<uintptr_t>(g));
    __builtin_amdgcn_global_load_lds(gl, lds, 16, 0, 0);
}

__device__ __forceinline__ void cvt8(float4 a, float4 b, bf16x8& h, bf16x8& l)
{
    float f[8] = {a.x, a.y, a.z, a.w, b.x, b.y, b.z, b.w};
#pragma unroll
    for (int j = 0; j < 8; ++j) {
        bf16_t hh = (bf16_t)f[j];
        h[j] = hh;
        l[j] = (bf16_t)(f[j] - (float)hh);
    }
}

// ---------------------------------------------------------------------------
// Kernel 0: pack W -> bf16 hi/lo in 32x32x16 B-fragment order.
//   frag f = n*2 + ks (n: 32-expert group, ks: K16 step);
//   lane l holds B[k = c*32 + ks*16 + (l>>5)*8 + j][e = n*32 + (l&31)]
// ---------------------------------------------------------------------------
__global__ __launch_bounds__(256)
void prep_w(const float* __restrict__ w, bf16_t* __restrict__ whi,
            bf16_t* __restrict__ wlo, int* __restrict__ cnt)
{
    const int gid = blockIdx.x * 256 + threadIdx.x;   // 229376
    if (gid == 0) *cnt = 0;
    const int c    = gid >> 10;
    const int rem  = gid & 1023;
    const int f    = rem >> 6;
    const int lane = rem & 63;
    const int e  = (f >> 1) * 32 + (lane & 31);
    const int k0 = c * 32 + (f & 1) * 16 + (lane >> 5) * 8;

    float4 f0 = *(const float4*)(w + (long)e * HID + k0);
    float4 f1 = *(const float4*)(w + (long)e * HID + k0 + 4);
    bf16x8 hv, lv;
    cvt8(f0, f1, hv, lv);
    *(bf16x8*)(whi + (long)gid * 8) = hv;
    *(bf16x8*)(wlo + (long)gid * 8) = lv;
}

// ---------------------------------------------------------------------------
// Kernel 1: MFMA gate + flags. 256 blocks x 512 threads.
// ---------------------------------------------------------------------------
__global__ __launch_bounds__(512, 2)
void gate_mfma(const float* __restrict__ x, const bf16_t* __restrict__ whi_p,
               const bf16_t* __restrict__ wlo_p, const float* __restrict__ bias,
               float* __restrict__ out, int* __restrict__ cnt,
               int* __restrict__ list)
{
    extern __shared__ __align__(16) char smem[];

    const int tid = threadIdx.x;
    const int bid = blockIdx.x;
    const int swz = (bid & 7) * 32 + (bid >> 3);   // XCD swizzle
    const long trow0 = (long)swz * BM1;

    const int lane  = tid & 63;
    const int wid   = tid >> 6;
    const int s_par = wid & 1;    // K-parity
    const int n4    = wid >> 1;   // expert-64 group 0..3

    // A staging map: threads 0-255 stage chunk q0, 256-511 stage q1.
    // u = tid&255: frag f=(u>>6)&3 (m=u>>7, ks=(u>>6)&1), entry lane = u&63
    const int u    = tid & 255;
    const int acid = tid >> 8;
    const int arow = ((u >> 7) & 1) * 32 + (u & 31);
    const int akof = ((u >> 6) & 1) * 16 + ((u >> 5) & 1) * 8;
    const float* xsrc = x + (trow0 + arow) * (long)HID + akof;
    const int af = (u >> 6) & 3;

    f32x16 acc[2][2] = {};

    auto stage_A = [&](int q) {   // wave-uniform q (cid folded by caller)
        float4 a = *(const float4*)(xsrc + q * BK1);
        float4 b = *(const float4*)(xsrc + q * BK1 + 4);
        bf16x8 h, l;
        cvt8(a, b, h, l);
        char* aw = smem + A_BASE + (q & 3) * 8192 + af * 1024 + (u & 63) * 16;
        *(bf16x8*)(aw)        = h;
        *(bf16x8*)(aw + 4096) = l;
    };
    auto stage_Bw = [&](int q) {  // wave stages its 2 frags, hi+lo
#pragma unroll
        for (int fi = 0; fi < 2; ++fi) {
            const int f = wid * 2 + fi;
            const long so = ((long)(q * 16 + f) << 9) + lane * 8;  // elements
            char* dst = smem + (q & 3) * 32768 + f * 1024 + lane * 16;
            async16(whi_p + so, dst);
            async16(wlo_p + so, dst + 16384);
        }
    };

    // ---- prologue: stage chunks 0,1 ----
    stage_A(acid);        // threads 0-255 -> chunk 0, 256-511 -> chunk 1
    stage_Bw(0);
    stage_Bw(1);

    // ---- phase loop ----
    for (int p = 0; p < NPH; ++p) {
        __syncthreads();   // drains vm+lgkm, then barrier

        const int myc  = 2 * p + s_par;
        const char* aS = smem + A_BASE + (myc & 3) * 8192;
        const char* bS = smem + (myc & 3) * 32768;

        bf16x8 ah[2][2], al[2][2], bh[2][2], bl[2][2];
#pragma unroll
        for (int mi = 0; mi < 2; ++mi)
#pragma unroll
            for (int ks = 0; ks < 2; ++ks) {
                ah[mi][ks] = *(const bf16x8*)(aS + (mi * 2 + ks) * 1024 + lane * 16);
                al[mi][ks] = *(const bf16x8*)(aS + 4096 + (mi * 2 + ks) * 1024 + lane * 16);
            }
#pragma unroll
        for (int ni = 0; ni < 2; ++ni)
#pragma unroll
            for (int ks = 0; ks < 2; ++ks) {
                const int f = (2 * n4 + ni) * 2 + ks;
                bh[ni][ks] = *(const bf16x8*)(bS + f * 1024 + lane * 16);
                bl[ni][ks] = *(const bf16x8*)(bS + 16384 + f * 1024 + lane * 16);
            }

        // staging for chunks 2p+2, 2p+3 (overlaps with MFMA below)
        {
            const int qa = 2 * p + 2 + acid;
            if (qa < NCH1) stage_A(qa);
            if (2 * p + 2 < NCH1) stage_Bw(2 * p + 2);
            if (2 * p + 3 < NCH1) stage_Bw(2 * p + 3);
        }

        __builtin_amdgcn_s_setprio(1);
#pragma unroll
        for (int ks = 0; ks < 2; ++ks)
#pragma unroll
            for (int mi = 0; mi < 2; ++mi)
#pragma unroll
                for (int ni = 0; ni < 2; ++ni)
                    acc[mi][ni] = __builtin_amdgcn_mfma_f32_32x32x16_bf16(
                        ah[mi][ks], bh[ni][ks], acc[mi][ni], 0, 0, 0);
#pragma unroll
        for (int ks = 0; ks < 2; ++ks)
#pragma unroll
            for (int mi = 0; mi < 2; ++mi)
#pragma unroll
                for (int ni = 0; ni < 2; ++ni)
                    acc[mi][ni] = __builtin_amdgcn_mfma_f32_32x32x16_bf16(
                        ah[mi][ks], bl[ni][ks], acc[mi][ni], 0, 0, 0);
#pragma unroll
        for (int ks = 0; ks < 2; ++ks)
#pragma unroll
            for (int mi = 0; mi < 2; ++mi)
#pragma unroll
                for (int ni = 0; ni < 2; ++ni)
                    acc[mi][ni] = __builtin_amdgcn_mfma_f32_32x32x16_bf16(
                        al[mi][ks], bh[ni][ks], acc[mi][ni], 0, 0, 0);
        __builtin_amdgcn_s_setprio(0);
    }
    __syncthreads();

    // ---- combine K-parity partials into logits LDS ----
    // 32x32 C/D map (verified m74): row = (r&3)+8*(r>>2)+4*(lane>>5), col = lane&31
    float* lgl = (float*)smem;
    const int rb = 4 * (lane >> 5);
    const int cb = n4 * 64 + (lane & 31);
    if (s_par == 0) {
#pragma unroll
        for (int mi = 0; mi < 2; ++mi)
#pragma unroll
            for (int ni = 0; ni < 2; ++ni)
#pragma unroll
                for (int r = 0; r < 16; ++r)
                    lgl[(mi * 32 + (r & 3) + 8 * (r >> 2) + rb) * LSTR +
                        cb + ni * 32] = acc[mi][ni][r];
    }
    __syncthreads();
    if (s_par == 1) {
#pragma unroll
        for (int mi = 0; mi < 2; ++mi)
#pragma unroll
            for (int ni = 0; ni < 2; ++ni)
#pragma unroll
                for (int r = 0; r < 16; ++r)
                    lgl[(mi * 32 + (r & 3) + 8 * (r >> 2) + rb) * LSTR +
                        cb + ni * 32] += acc[mi][ni][r];
    }
    __syncthreads();

    // ---- gating (proven fp32) + margin flags; half-wave = 4 tokens ----
    const int l     = tid & 31;
    const int hbase = lane & 32;
    const int myGLo = l >> 3;
    const int m0    = (tid >> 5) * 4;

    float bb[8];
    {
        float4 b0 = *(const float4*)&bias[4 * l];
        float4 b1 = *(const float4*)&bias[4 * l + 128];
        bb[0] = b0.x; bb[1] = b0.y; bb[2] = b0.z; bb[3] = b0.w;
        bb[4] = b1.x; bb[5] = b1.y; bb[6] = b1.z; bb[7] = b1.w;
    }

    float* out_idx = out;
    float* out_w   = out + (long)T_TOT * 8;

    for (int i = 0; i < 4; ++i) {
        const long t = trow0 + m0 + i;
        float4 lg0 = *(const float4*)&lgl[(m0 + i) * LSTR + 4 * l];
        float4 lg1 = *(const float4*)&lgl[(m0 + i) * LSTR + 128 + 4 * l];
        float lgv[8] = {lg0.x, lg0.y, lg0.z, lg0.w, lg1.x, lg1.y, lg1.z, lg1.w};
        float sc[8], cs[8];
#pragma unroll
        for (int j = 0; j < 8; ++j) {
            sc[j] = 1.0f / (1.0f + expf(-lgv[j]));
            cs[j] = sc[j] + bb[j];
        }
        float l1, l2, h1, h2;
        {
            l1 = fmaxf(cs[0], cs[1]); l2 = fminf(cs[0], cs[1]);
            float n1 = fmaxf(l1, cs[2]); float n2 = fmaxf(fminf(l1, cs[2]), l2); l1 = n1; l2 = n2;
            n1 = fmaxf(l1, cs[3]); n2 = fmaxf(fminf(l1, cs[3]), l2); l1 = n1; l2 = n2;
            h1 = fmaxf(cs[4], cs[5]); h2 = fminf(cs[4], cs[5]);
            n1 = fmaxf(h1, cs[6]); n2 = fmaxf(fminf(h1, cs[6]), h2); h1 = n1; h2 = n2;
            n1 = fmaxf(h1, cs[7]); n2 = fmaxf(fminf(h1, cs[7]), h2); h1 = n1; h2 = n2;
        }
#pragma unroll
        for (int d = 1; d < 8; d <<= 1) {
            float o1 = __shfl_xor(l1, d), o2 = __shfl_xor(l2, d);
            float n1 = fmaxf(l1, o1);
            float n2 = fmaxf(fminf(l1, o1), fmaxf(l2, o2));
            l1 = n1; l2 = n2;
            o1 = __shfl_xor(h1, d); o2 = __shfl_xor(h2, d);
            n1 = fmaxf(h1, o1);
            n2 = fmaxf(fminf(h1, o1), fmaxf(h2, o2));
            h1 = n1; h2 = n2;
        }
        const float gLo = l1 + l2;
        const float gHi = h1 + h2;

        int rLo = 0, rHi = 0;
#pragma unroll
        for (int g = 0; g < 8; ++g) {
            float v = (g < 4) ? __shfl(gLo, hbase + g * 8)
                              : __shfl(gHi, hbase + (g - 4) * 8);
            rLo += (v > gLo || (v == gLo && g < myGLo)) ? 1 : 0;
            rHi += (v > gHi || (v == gHi && g < myGLo + 4)) ? 1 : 0;
        }
        const bool selLo = (rLo < 4);
        const bool selHi = (rHi < 4);

        float selMin =  INFINITY, unsMax = -INFINITY;
        if (selLo) selMin = gLo; else unsMax = gLo;
        if (selHi) selMin = fminf(selMin, gHi); else unsMax = fmaxf(unsMax, gHi);
#pragma unroll
        for (int d = 1; d < 32; d <<= 1) {
            selMin = fminf(selMin, __shfl_xor(selMin, d));
            unsMax = fmaxf(unsMax, __shfl_xor(unsMax, d));
        }
        const float ggap = selMin - unsMax;

        float mv[8];
#pragma unroll
        for (int j = 0; j < 8; ++j)
            mv[j] = ((j < 4) ? selLo : selHi) ? cs[j] : -INFINITY;

        float wsum = 0.0f, my_w = 0.0f;
        int my_ii = 0;
        float prevv = 0.0f, mingap = INFINITY;
#pragma unroll
        for (int k = 0; k < 9; ++k) {
            float bv = mv[0]; int bj = 0;
            if (mv[1] > bv) { bv = mv[1]; bj = 1; }
            if (mv[2] > bv) { bv = mv[2]; bj = 2; }
            if (mv[3] > bv) { bv = mv[3]; bj = 3; }
            if (mv[4] > bv) { bv = mv[4]; bj = 4; }
            if (mv[5] > bv) { bv = mv[5]; bj = 5; }
            if (mv[6] > bv) { bv = mv[6]; bj = 6; }
            if (mv[7] > bv) { bv = mv[7]; bj = 7; }
            float v = bv;
            int ii = (bj < 4) ? (4 * l + bj) : (128 + 4 * l + (bj - 4));
#pragma unroll
            for (int d = 1; d < 32; d <<= 1) {
                float ov = __shfl_xor(v, d);
                int   oi = __shfl_xor(ii, d);
                if (ov > v || (ov == v && oi < ii)) { v = ov; ii = oi; }
            }
            if (k) mingap = fminf(mingap, prevv - v);
            prevv = v;
            if (k < 8) {
                const int hi8 = ii >> 7;
                const int oj  = (ii & 3) + 4 * hi8;
                const int ol  = (ii & 127) >> 2;
                float ssel = (oj == 0) ? sc[0] : (oj == 1) ? sc[1] : (oj == 2) ? sc[2] :
                             (oj == 3) ? sc[3] : (oj == 4) ? sc[4] : (oj == 5) ? sc[5] :
                             (oj == 6) ? sc[6] : sc[7];
                float su = __shfl(ssel, hbase + ol);
                wsum += su;
                if (l == k) { my_ii = ii; my_w = su; }
#pragma unroll
                for (int j = 0; j < 8; ++j) {
                    int jj = (j < 4) ? (4 * l + j) : (128 + 4 * l + (j - 4));
                    if (jj == ii) mv[j] = -INFINITY;
                }
            }
        }

        const float scale = 2.5f / (wsum + 1e-20f);
        if (l < 8) {
            out_idx[t * 8 + l] = (float)my_ii;
            out_w[t * 8 + l]   = my_w * scale;
        }
        const bool flag = (mingap < ETHR) || (ggap < GTHR);
        if (flag && l == 0) {
            int pos = atomicAdd(cnt, 1);
            if (pos < LISTCAP) list[pos] = (int)t;
        }
    }
}

// ---------------------------------------------------------------------------
// Kernel 2: fp64 partial dots for flagged tokens (K-split)
// ---------------------------------------------------------------------------
__global__ __launch_bounds__(256)
void repair_partial(const float* __restrict__ x, const float* __restrict__ w,
                    const int* __restrict__ list, const int* __restrict__ cntp,
                    double* __restrict__ part, int base, int cap)
{
    __shared__ __align__(16) float xls[TB2 * SEGK];
    __shared__ int tokls[TB2];
    const int tid = threadIdx.x;
    const int ks  = blockIdx.y;

    int cnt = *cntp;
    if (cnt > LISTCAP) cnt = LISTCAP;
    const int cEnd = min(cnt, base + cap);

    for (int s0 = base + blockIdx.x * TB2; s0 < cEnd; s0 += gridDim.x * TB2) {
        if (tid < TB2) {
            int slot = s0 + tid;
            tokls[tid] = (slot < cEnd) ? list[slot] : 0;
        }
        __syncthreads();
        for (int q = tid; q < TB2 * (SEGK / 4); q += 256) {
            int i = q / (SEGK / 4), f = q % (SEGK / 4);
            float4 v = *(const float4*)(x + (long)tokls[i] * HID + ks * SEGK + f * 4);
            *(float4*)&xls[i * SEGK + f * 4] = v;
        }
        __syncthreads();

        double acc[TB2];
#pragma unroll
        for (int i = 0; i < TB2; ++i) acc[i] = 0.0;

        const float4* wp = (const float4*)(w + (long)tid * HID + ks * SEGK);
        for (int kb = 0; kb < SEGK / 4; ++kb) {
            float4 wv = wp[kb];
            double w0 = wv.x, w1 = wv.y, w2 = wv.z, w3 = wv.w;
#pragma unroll
            for (int i = 0; i < TB2; ++i) {
                float4 xv = *(const float4*)&xls[i * SEGK + kb * 4];
                acc[i] = fma((double)xv.x, w0, acc[i]);
                acc[i] = fma((double)xv.y, w1, acc[i]);
                acc[i] = fma((double)xv.z, w2, acc[i]);
                acc[i] = fma((double)xv.w, w3, acc[i]);
            }
        }
#pragma unroll
        for (int i = 0; i < TB2; ++i) {
            long pofs = (((long)(s0 - base) + i) * KSEG + ks) * NEXP + tid;
            part[pofs] = acc[i];
        }
        __syncthreads();
    }
}

// ---------------------------------------------------------------------------
// Kernel 3: reduce partials + exact fp64 gating for flagged tokens
// ---------------------------------------------------------------------------
__global__ __launch_bounds__(256)
void repair_gate(const float* __restrict__ bias, const int* __restrict__ list,
                 const int* __restrict__ cntp, const double* __restrict__ part,
                 float* __restrict__ out, int base, int cap)
{
    __shared__ double lgl[TBG * NEXP];
    __shared__ int tokls[TBG];
    const int tid = threadIdx.x;

    int cnt = *cntp;
    if (cnt > LISTCAP) cnt = LISTCAP;
    const int cEnd = min(cnt, base + cap);

    float* out_idx = out;
    float* out_w   = out + (long)T_TOT * 8;

    const int l     = tid & 31;
    const int lane  = tid & 63;
    const int hbase = lane & 32;
    const int hw    = tid >> 5;
    const int myGLo = l >> 3;

    double bb[8];
    {
        float4 b0 = *(const float4*)&bias[4 * l];
        float4 b1 = *(const float4*)&bias[4 * l + 128];
        bb[0] = b0.x; bb[1] = b0.y; bb[2] = b0.z; bb[3] = b0.w;
        bb[4] = b1.x; bb[5] = b1.y; bb[6] = b1.z; bb[7] = b1.w;
    }

    for (int s0 = base + blockIdx.x * TBG; s0 < cEnd; s0 += gridDim.x * TBG) {
        if (tid < TBG) {
            int slot = s0 + tid;
            tokls[tid] = (slot < cEnd) ? list[slot] : 0;
        }
#pragma unroll
        for (int i = 0; i < TBG; ++i) {
            long pbase = (((long)(s0 - base) + i) * KSEG) * NEXP + tid;
            double s = 0.0;
#pragma unroll
            for (int ks = 0; ks < KSEG; ++ks) s += part[pbase + ks * NEXP];
            lgl[i * NEXP + tid] = s;
        }
        __syncthreads();
        {
            const int slot = s0 + hw;
            const bool valid = (slot < cEnd);
            const long t = tokls[hw];

            double sc[8], cs[8];
#pragma unroll
            for (int j = 0; j < 4; ++j) {
                double lg = lgl[hw * NEXP + 4 * l + j];
                sc[j] = 1.0 / (1.0 + exp(-lg));
                cs[j] = sc[j] + bb[j];
            }
#pragma unroll
            for (int j = 4; j < 8; ++j) {
                double lg = lgl[hw * NEXP + 128 + 4 * l + (j - 4)];
                sc[j] = 1.0 / (1.0 + exp(-lg));
                cs[j] = sc[j] + bb[j];
            }

            double l1, l2, h1, h2;
            {
                l1 = fmax(cs[0], cs[1]); l2 = fmin(cs[0], cs[1]);
                double n1 = fmax(l1, cs[2]); double n2 = fmax(fmin(l1, cs[2]), l2); l1 = n1; l2 = n2;
                n1 = fmax(l1, cs[3]); n2 = fmax(fmin(l1, cs[3]), l2); l1 = n1; l2 = n2;
                h1 = fmax(cs[4], cs[5]); h2 = fmin(cs[4], cs[5]);
                n1 = fmax(h1, cs[6]); n2 = fmax(fmin(h1, cs[6]), h2); h1 = n1; h2 = n2;
                n1 = fmax(h1, cs[7]); n2 = fmax(fmin(h1, cs[7]), h2); h1 = n1; h2 = n2;
            }
#pragma unroll
            for (int d = 1; d < 8; d <<= 1) {
                double o1 = __shfl_xor(l1, d), o2 = __shfl_xor(l2, d);
                double n1 = fmax(l1, o1);
                double n2 = fmax(fmin(l1, o1), fmax(l2, o2));
                l1 = n1; l2 = n2;
                o1 = __shfl_xor(h1, d); o2 = __shfl_xor(h2, d);
                n1 = fmax(h1, o1);
                n2 = fmax(fmin(h1, o1), fmax(h2, o2));
                h1 = n1; h2 = n2;
            }
            const double gLo = l1 + l2;
            const double gHi = h1 + h2;

            int rLo = 0, rHi = 0;
#pragma unroll
            for (int g = 0; g < 8; ++g) {
                double v = (g < 4) ? __shfl(gLo, hbase + g * 8)
                                   : __shfl(gHi, hbase + (g - 4) * 8);
                rLo += (v > gLo || (v == gLo && g < myGLo)) ? 1 : 0;
                rHi += (v > gHi || (v == gHi && g < myGLo + 4)) ? 1 : 0;
            }
            const bool selLo = (rLo < 4);
            const bool selHi = (rHi < 4);

            double mv[8];
#pragma unroll
            for (int j = 0; j < 8; ++j)
                mv[j] = ((j < 4) ? selLo : selHi) ? cs[j] : -INFINITY;

            double wsum = 0.0, my_w = 0.0;
            int my_ii = 0;
#pragma unroll
            for (int k = 0; k < 8; ++k) {
                double bv = mv[0]; int bj = 0;
                if (mv[1] > bv) { bv = mv[1]; bj = 1; }
                if (mv[2] > bv) { bv = mv[2]; bj = 2; }
                if (mv[3] > bv) { bv = mv[3]; bj = 3; }
                if (mv[4] > bv) { bv = mv[4]; bj = 4; }
                if (mv[5] > bv) { bv = mv[5]; bj = 5; }
                if (mv[6] > bv) { bv = mv[6]; bj = 6; }
                if (mv[7] > bv) { bv = mv[7]; bj = 7; }
                double v = bv;
                int ii = (bj < 4) ? (4 * l + bj) : (128 + 4 * l + (bj - 4));
#pragma unroll
                for (int d = 1; d < 32; d <<= 1) {
                    double ov = __shfl_xor(v, d);
                    int    oi = __shfl_xor(ii, d);
                    if (ov > v || (ov == v && oi < ii)) { v = ov; ii = oi; }
                }
                const int hi8 = ii >> 7;
                const int oj  = (ii & 3) + 4 * hi8;
                const int ol  = (ii & 127) >> 2;
                double ssel = (oj == 0) ? sc[0] : (oj == 1) ? sc[1] : (oj == 2) ? sc[2] :
                              (oj == 3) ? sc[3] : (oj == 4) ? sc[4] : (oj == 5) ? sc[5] :
                              (oj == 6) ? sc[6] : sc[7];
                double su = __shfl(ssel, hbase + ol);
                wsum += su;
                if (l == k) { my_ii = ii; my_w = su; }
#pragma unroll
                for (int j = 0; j < 8; ++j) {
                    int jj = (j < 4) ? (4 * l + j) : (128 + 4 * l + (j - 4));
                    if (jj == ii) mv[j] = -INFINITY;
                }
            }

            const double scale = 2.5 / (wsum + 1e-20);
            if (valid && l < 8) {
                out_idx[t * 8 + l] = (float)my_ii;
                out_w[t * 8 + l]   = (float)(my_w * scale);
            }
        }
        __syncthreads();
    }
}

// ---------------------------------------------------------------------------
extern "C" void kernel_launch(void* const* d_in, const int* in_sizes, int n_in,
                              void* d_out, int out_size, void* d_ws, size_t ws_size,
                              hipStream_t stream)
{
    const float* x    = (const float*)d_in[0];
    const float* w    = (const float*)d_in[1];
    const float* bias = (const float*)d_in[2];
    float* out = (float*)d_out;

    int*    cnt  = (int*)d_ws;
    int*    list = (int*)((char*)d_ws + 256);
    bf16_t* whi  = (bf16_t*)((char*)d_ws + 66048);
    bf16_t* wlo  = (bf16_t*)((char*)d_ws + 66048 + 3670016);
    double* part = (double*)((char*)d_ws + 7406080);

    size_t avail = (ws_size > 7406080) ? (ws_size - 7406080) : 0;
    long cap_l = (long)(avail / ((size_t)KSEG * NEXP * 8));
    int CAP = (int)(cap_l > 4096 ? 4096 : cap_l);

    prep_w<<<896, 256, 0, stream>>>(w, whi, wlo, cnt);
    gate_mfma<<<256, 512, SMEM_SZ, stream>>>(x, whi, wlo, bias, out, cnt, list);
    if (CAP > 0) {
        repair_partial<<<dim3(16, KSEG), 256, 0, stream>>>(x, w, list, cnt, part, 0, CAP);
        repair_gate<<<32, 256, 0, stream>>>(bias, list, cnt, part, out, 0, CAP);
    }
}